// Round 4
// baseline (926.958 us; speedup 1.0000x reference)
//
#include <hip/hip_runtime.h>

// GCN pipeline on MI355X, round 4 (round-3 resubmit after infra failure):
//   deg/dinv -> CSR(by dst, packed int2) -> GEMM1 (barrier-free register-panel,
//   f16 MFMA, fp32 A cvt in regs) -> agg+relu(f16, 4-chain) -> GEMM2 -> agg+relu
//   -> BN stats -> fused BN+LN -> out(fp32)
// B is pre-shuffled into MFMA-fragment-linear layout so a B-frag load is one
// coalesced dwordx4/lane. No LDS, no __syncthreads in the GEMM K-loop => the
// compiler pipelines loads with fine-grained vmcnt (no barrier vmcnt(0) drain).

typedef __attribute__((ext_vector_type(4))) float f32x4;
typedef __attribute__((ext_vector_type(8))) _Float16 f16x8;
typedef __attribute__((ext_vector_type(4))) _Float16 f16x4;

#define NN 50000
#define NF 1024
#define NH 256

// ---------------- degree / dinv ----------------------------------------------
__global__ __launch_bounds__(256) void deg_count(const int* __restrict__ ei,
    const float* __restrict__ ew, float* __restrict__ deg, int* __restrict__ cnt, int E)
{
    int e = blockIdx.x * 256 + threadIdx.x;
    if (e >= E) return;
    int d = ei[E + e];
    atomicAdd(&deg[d], ew[e]);
    atomicAdd(&cnt[d], 1);
}

__global__ __launch_bounds__(256) void dinv_k(const float* __restrict__ deg,
    float* __restrict__ dinv, int n)
{
    int i = blockIdx.x * 256 + threadIdx.x;
    if (i < n) dinv[i] = rsqrtf(deg[i] + 1.0f);   // +1 = self-loop weight
}

// ---------------- CSR build: scan + scatter ----------------------------------
__global__ __launch_bounds__(512) void scan_a(const int* __restrict__ cnt,
    int* __restrict__ excl, int* __restrict__ bsum, int n)
{
    __shared__ int sm[512];
    int t = threadIdx.x, g = blockIdx.x * 512 + t;
    int v = (g < n) ? cnt[g] : 0;
    sm[t] = v;
    __syncthreads();
    for (int d = 1; d < 512; d <<= 1) {
        int x = (t >= d) ? sm[t - d] : 0;
        __syncthreads();
        sm[t] += x;
        __syncthreads();
    }
    if (g < n) excl[g] = sm[t] - v;
    if (t == 511) bsum[blockIdx.x] = sm[511];
}

__global__ __launch_bounds__(128) void scan_b(int* __restrict__ bsum, int nb)
{
    __shared__ int sm[128];
    int t = threadIdx.x;
    int v = (t < nb) ? bsum[t] : 0;
    sm[t] = v;
    __syncthreads();
    for (int d = 1; d < 128; d <<= 1) {
        int x = (t >= d) ? sm[t - d] : 0;
        __syncthreads();
        sm[t] += x;
        __syncthreads();
    }
    if (t < nb) bsum[t] = sm[t] - v;
}

__global__ __launch_bounds__(256) void scan_c(const int* __restrict__ excl,
    const int* __restrict__ bsum, int* __restrict__ offs, int n, int E)
{
    int g = blockIdx.x * 256 + threadIdx.x;
    if (g < n) offs[g] = excl[g] + bsum[g >> 9];
    else if (g == n) offs[n] = E;
}

__global__ __launch_bounds__(256) void scatter_k(const int* __restrict__ ei,
    const float* __restrict__ ew, const int* __restrict__ offs,
    int* __restrict__ cursor, const float* __restrict__ dinv,
    int2* __restrict__ eadj, int E)
{
    int e = blockIdx.x * 256 + threadIdx.x;
    if (e >= E) return;
    int s = ei[e], d = ei[E + e];
    int pos = offs[d] + atomicAdd(&cursor[d], 1);
    float w = ew[e] * dinv[s] * dinv[d];
    eadj[pos] = make_int2(s, __float_as_int(w));   // one 8-B store
}

// ---------------- W -> fragment-linear f16 B panel ---------------------------
// In: W [K][256] fp32 row-major. Out: BF[kt][j][lane][8] f16 where
//   k = kt*32 + q*8 + e, n = j*16 + r, lane = q*16 + r.
// A B-frag load in the GEMM is then BF + kt*8192 + j*512 + lane*8 (coalesced).
__global__ __launch_bounds__(256) void cvt_w_frag(const float* __restrict__ W,
    _Float16* __restrict__ BF, int total)
{
    int idx = blockIdx.x * 256 + threadIdx.x;
    if (idx >= total) return;
    int k = idx >> 8, n = idx & 255;
    int kt = k >> 5, q = (k >> 3) & 3, e = k & 7;
    int j = n >> 4, r = n & 15;
    BF[(size_t)kt * 8192 + j * 512 + q * 128 + r * 8 + e] = (_Float16)W[idx];
}

// ---------------- barrier-free register-panel GEMM ---------------------------
// C[M][256](f16) = A[M][K] * B. One wave owns 16 rows x 256 cols (16 n-tiles,
// 64 accs). Per k-tile: 1 A-frag (16B/lane, dist-2 reg prefetch) + 16 B-frag
// loads (coalesced dwordx4 from L2-hot BF) + 16 MFMA. No LDS, no barriers.
template<bool AF32>
__global__ __launch_bounds__(256) void gemm_reg(
    const void* __restrict__ Av, const _Float16* __restrict__ BF,
    _Float16* __restrict__ C, int M, int K)
{
    const int t = threadIdx.x;
    const int lane = t & 63, wid = t >> 6;
    const int r = lane & 15, q = lane >> 4;
    const int m0 = (blockIdx.x * 4 + wid) << 4;
    if (m0 >= M) return;                       // wave-uniform exit

    const int T = K >> 5;                      // k-tiles (32 or 8) - always even
    f32x4 acc[16];
#pragma unroll
    for (int j = 0; j < 16; ++j) acc[j] = (f32x4){0.f, 0.f, 0.f, 0.f};

    const float* apf;
    const _Float16* aph;
    if constexpr (AF32) apf = (const float*)Av + (size_t)(m0 + r) * K + q * 8;
    else                aph = (const _Float16*)Av + (size_t)(m0 + r) * K + q * 8;

    float4 p0a, p0b, p1a, p1b;   // fp32 prefetch (distance 2)
    f16x8 h0, h1;                // f16 prefetch
    if constexpr (AF32) {
        p0a = *(const float4*)(apf + 0);  p0b = *(const float4*)(apf + 4);
        p1a = *(const float4*)(apf + 32); p1b = *(const float4*)(apf + 36);
    } else {
        h0 = *(const f16x8*)(aph + 0);
        h1 = *(const f16x8*)(aph + 32);
    }

    for (int kt = 0; kt < T; kt += 2) {
        // -------- even k-tile --------
        f16x8 a;
        if constexpr (AF32) {
#pragma unroll
            for (int e = 0; e < 4; ++e) {
                a[e]     = (_Float16)(&p0a.x)[e];
                a[4 + e] = (_Float16)(&p0b.x)[e];
            }
        } else a = h0;
        {
            int kn = (kt + 2 < T) ? kt + 2 : 0;   // clamp: dummy reload, unused
            if constexpr (AF32) {
                p0a = *(const float4*)(apf + (size_t)kn * 32);
                p0b = *(const float4*)(apf + (size_t)kn * 32 + 4);
            } else h0 = *(const f16x8*)(aph + (size_t)kn * 32);
        }
        const _Float16* bb = BF + (size_t)kt * 8192 + lane * 8;
#pragma unroll
        for (int j = 0; j < 16; ++j) {
            f16x8 bf = *(const f16x8*)(bb + j * 512);
            acc[j] = __builtin_amdgcn_mfma_f32_16x16x32_f16(a, bf, acc[j], 0, 0, 0);
        }
        // -------- odd k-tile --------
        if constexpr (AF32) {
#pragma unroll
            for (int e = 0; e < 4; ++e) {
                a[e]     = (_Float16)(&p1a.x)[e];
                a[4 + e] = (_Float16)(&p1b.x)[e];
            }
        } else a = h1;
        {
            int kn = (kt + 3 < T) ? kt + 3 : 0;
            if constexpr (AF32) {
                p1a = *(const float4*)(apf + (size_t)kn * 32);
                p1b = *(const float4*)(apf + (size_t)kn * 32 + 4);
            } else h1 = *(const f16x8*)(aph + (size_t)kn * 32);
        }
        const _Float16* bb2 = bb + 8192;
#pragma unroll
        for (int j = 0; j < 16; ++j) {
            f16x8 bf = *(const f16x8*)(bb2 + j * 512);
            acc[j] = __builtin_amdgcn_mfma_f32_16x16x32_f16(a, bf, acc[j], 0, 0, 0);
        }
    }

    // epilogue: C/D layout row=q*4+reg, col=r per 16x16 tile
    _Float16* crow = C + (size_t)(m0 + q * 4) * 256 + r;
#pragma unroll
    for (int j = 0; j < 16; ++j)
#pragma unroll
        for (int reg = 0; reg < 4; ++reg)
            crow[(size_t)reg * 256 + j * 16] = (_Float16)acc[j][reg];
}

// ---------------- aggregation: out = relu(A_hat @ h + b), f16 ----------------
// 1 wave/node, lane = 4 cols. Edge (src,w) packed int2, loaded coalesced per
// 64-edge chunk, broadcast via shfl; 4 independent gather chains.
__global__ __launch_bounds__(256) void agg_relu(
    const _Float16* __restrict__ h, const int* __restrict__ roff,
    const int2* __restrict__ eadj, const float* __restrict__ dinv,
    const float* __restrict__ bias, _Float16* __restrict__ out, int n)
{
    const int lane = threadIdx.x & 63, wid = threadIdx.x >> 6;
    const int i = blockIdx.x * 4 + wid;
    if (i >= n) return;
    const int c = lane << 2;
    const float di = dinv[i];
    const float sw = di * di;
    const f16x4 hv = *(const f16x4*)(h + (size_t)i * 256 + c);
    float a0 = sw * (float)hv.x, a1 = sw * (float)hv.y;
    float a2 = sw * (float)hv.z, a3 = sw * (float)hv.w;
    float b0 = 0.f, b1 = 0.f, b2 = 0.f, b3 = 0.f;
    float c0 = 0.f, c1 = 0.f, c2 = 0.f, c3 = 0.f;
    float d0 = 0.f, d1 = 0.f, d2 = 0.f, d3 = 0.f;
    const int p0 = roff[i], pe = roff[i + 1];
    for (int base = p0; base < pe; base += 64) {
        int lim = pe - base; if (lim > 64) lim = 64;
        int sv = 0; float wv = 0.f;
        if (lane < lim) {
            int2 ev = eadj[base + lane];
            sv = ev.x; wv = __int_as_float(ev.y);
        }
        int j = 0;
        for (; j + 3 < lim; j += 4) {
            int s0 = __shfl(sv, j), s1 = __shfl(sv, j + 1);
            int s2 = __shfl(sv, j + 2), s3 = __shfl(sv, j + 3);
            float w0 = __shfl(wv, j), w1 = __shfl(wv, j + 1);
            float w2 = __shfl(wv, j + 2), w3 = __shfl(wv, j + 3);
            f16x4 v0 = *(const f16x4*)(h + (size_t)s0 * 256 + c);
            f16x4 v1 = *(const f16x4*)(h + (size_t)s1 * 256 + c);
            f16x4 v2 = *(const f16x4*)(h + (size_t)s2 * 256 + c);
            f16x4 v3 = *(const f16x4*)(h + (size_t)s3 * 256 + c);
            a0 += w0 * (float)v0.x; a1 += w0 * (float)v0.y;
            a2 += w0 * (float)v0.z; a3 += w0 * (float)v0.w;
            b0 += w1 * (float)v1.x; b1 += w1 * (float)v1.y;
            b2 += w1 * (float)v1.z; b3 += w1 * (float)v1.w;
            c0 += w2 * (float)v2.x; c1 += w2 * (float)v2.y;
            c2 += w2 * (float)v2.z; c3 += w2 * (float)v2.w;
            d0 += w3 * (float)v3.x; d1 += w3 * (float)v3.y;
            d2 += w3 * (float)v3.z; d3 += w3 * (float)v3.w;
        }
        for (; j < lim; ++j) {
            int s0 = __shfl(sv, j);
            float w0 = __shfl(wv, j);
            f16x4 v0 = *(const f16x4*)(h + (size_t)s0 * 256 + c);
            a0 += w0 * (float)v0.x; a1 += w0 * (float)v0.y;
            a2 += w0 * (float)v0.z; a3 += w0 * (float)v0.w;
        }
    }
    const float4 bb = *(const float4*)(bias + c);
    f16x4 o;
    o.x = (_Float16)fmaxf(a0 + b0 + c0 + d0 + bb.x, 0.f);
    o.y = (_Float16)fmaxf(a1 + b1 + c1 + d1 + bb.y, 0.f);
    o.z = (_Float16)fmaxf(a2 + b2 + c2 + d2 + bb.z, 0.f);
    o.w = (_Float16)fmaxf(a3 + b3 + c3 + d3 + bb.w, 0.f);
    *(f16x4*)(out + (size_t)i * 256 + c) = o;
}

// ---------------- BatchNorm stats --------------------------------------------
__global__ __launch_bounds__(256) void bn_stats(const _Float16* __restrict__ h,
    float* __restrict__ bnsum, float* __restrict__ bnsq, int n)
{
    const int t = threadIdx.x;
    float s = 0.f, s2 = 0.f;
    for (int r = blockIdx.x; r < n; r += gridDim.x) {
        float v = (float)h[(size_t)r * 256 + t];
        s += v; s2 += v * v;
    }
    atomicAdd(&bnsum[t], s);
    atomicAdd(&bnsq[t], s2);
}

__global__ __launch_bounds__(256) void bn_params(const float* __restrict__ bnsum,
    const float* __restrict__ bnsq, const float* __restrict__ gamma,
    const float* __restrict__ beta, float* __restrict__ scale,
    float* __restrict__ shift, int n)
{
    int t = threadIdx.x;
    float mu = bnsum[t] / (float)n;
    float var = bnsq[t] / (float)n - mu * mu;
    float sc = gamma[t] * rsqrtf(var + 1e-5f);
    scale[t] = sc;
    shift[t] = beta[t] - mu * sc;
}

// ---------------- fused BN affine + LayerNorm --------------------------------
__global__ __launch_bounds__(256) void bn_ln(const _Float16* __restrict__ h,
    const float* __restrict__ scale, const float* __restrict__ shift,
    const float* __restrict__ lng, const float* __restrict__ lnb,
    float* __restrict__ out, int n)
{
    const int lane = threadIdx.x & 63, wid = threadIdx.x >> 6;
    const int i = blockIdx.x * 4 + wid;
    if (i >= n) return;
    const int c = lane << 2;
    const f16x4 v = *(const f16x4*)(h + (size_t)i * 256 + c);
    const float4 sc = *(const float4*)(scale + c);
    const float4 sh = *(const float4*)(shift + c);
    float y0 = (float)v.x * sc.x + sh.x;
    float y1 = (float)v.y * sc.y + sh.y;
    float y2 = (float)v.z * sc.z + sh.z;
    float y3 = (float)v.w * sc.w + sh.w;
    float ps = y0 + y1 + y2 + y3;
    float ps2 = y0 * y0 + y1 * y1 + y2 * y2 + y3 * y3;
#pragma unroll
    for (int off = 32; off > 0; off >>= 1) {
        ps += __shfl_down(ps, off);
        ps2 += __shfl_down(ps2, off);
    }
    ps = __shfl(ps, 0);
    ps2 = __shfl(ps2, 0);
    const float mu = ps * (1.f / 256.f);
    const float var = ps2 * (1.f / 256.f) - mu * mu;
    const float rs = rsqrtf(var + 1e-5f);
    const float4 g = *(const float4*)(lng + c);
    const float4 bb = *(const float4*)(lnb + c);
    float4 o;
    o.x = (y0 - mu) * rs * g.x + bb.x;
    o.y = (y1 - mu) * rs * g.y + bb.y;
    o.z = (y2 - mu) * rs * g.z + bb.z;
    o.w = (y3 - mu) * rs * g.w + bb.w;
    *(float4*)(out + (size_t)i * 256 + c) = o;
}

// ---------------- launcher ---------------------------------------------------
extern "C" void kernel_launch(void* const* d_in, const int* in_sizes, int n_in,
                              void* d_out, int out_size, void* d_ws, size_t ws_size,
                              hipStream_t stream)
{
    const float* x   = (const float*)d_in[0];
    const int*   ei  = (const int*)d_in[1];
    const float* ew  = (const float*)d_in[2];
    const float* W1  = (const float*)d_in[3];
    const float* b1  = (const float*)d_in[4];
    const float* W2  = (const float*)d_in[5];
    const float* b2  = (const float*)d_in[6];
    const float* bng = (const float*)d_in[7];
    const float* bnb = (const float*)d_in[8];
    const float* lng = (const float*)d_in[9];
    const float* lnb = (const float*)d_in[10];
    float* out = (float*)d_out;

    const int N = NN;
    const int E = in_sizes[2];

    char* ws = (char*)d_ws;
    size_t o = 0;
    auto alloc = [&](size_t b) -> char* {
        char* p = ws + o;
        o = (o + b + 255) & ~(size_t)255;
        return p;
    };
    _Float16* h1  = (_Float16*)alloc((size_t)N * NH * 2);   // GEMM out (reused)
    _Float16* h1a = (_Float16*)alloc((size_t)N * NH * 2);
    _Float16* h2a = (_Float16*)alloc((size_t)N * NH * 2);
    _Float16* BF1 = (_Float16*)alloc((size_t)NH * NF * 2);
    _Float16* BF2 = (_Float16*)alloc((size_t)NH * NH * 2);
    int2*  eadj = (int2*)alloc((size_t)E * 8);
    int*   offs = (int*)alloc((size_t)(N + 1) * 4);
    int*   excl = (int*)alloc((size_t)N * 4);
    int*   bsum = (int*)alloc(512);
    float* dinv = (float*)alloc((size_t)N * 4);
    float* bnscale = (float*)alloc(NH * 4);
    float* bnshift = (float*)alloc(NH * 4);
    char* zbase = ws + o;
    float* deg    = (float*)alloc((size_t)N * 4);
    int*   cnt    = (int*)alloc((size_t)N * 4);
    int*   cursor = (int*)alloc((size_t)N * 4);
    float* bnsum  = (float*)alloc(NH * 4);
    float* bnsq   = (float*)alloc(NH * 4);
    size_t zbytes = (size_t)((ws + o) - zbase);
    (void)hipMemsetAsync(zbase, 0, zbytes, stream);

    cvt_w_frag<<<(NF * NH + 255) / 256, 256, 0, stream>>>(W1, BF1, NF * NH);
    cvt_w_frag<<<(NH * NH + 255) / 256, 256, 0, stream>>>(W2, BF2, NH * NH);
    deg_count<<<(E + 255) / 256, 256, 0, stream>>>(ei, ew, deg, cnt, E);
    dinv_k<<<(N + 255) / 256, 256, 0, stream>>>(deg, dinv, N);
    scan_a<<<(N + 511) / 512, 512, 0, stream>>>(cnt, excl, bsum, N);
    scan_b<<<1, 128, 0, stream>>>(bsum, (N + 511) / 512);
    scan_c<<<(N + 1 + 255) / 256, 256, 0, stream>>>(excl, bsum, offs, N, E);
    scatter_k<<<(E + 255) / 256, 256, 0, stream>>>(ei, ew, offs, cursor, dinv, eadj, E);

    const int ng = (N / 16 + 3) / 4;    // 782 blocks, 4 waves (16 rows) each
    gemm_reg<true><<<ng, 256, 0, stream>>>(x, BF1, h1, N, NF);
    agg_relu<<<(N + 3) / 4, 256, 0, stream>>>(h1, offs, eadj, dinv, b1, h1a, N);
    gemm_reg<false><<<ng, 256, 0, stream>>>(h1a, BF2, h1, N, NH);
    agg_relu<<<(N + 3) / 4, 256, 0, stream>>>(h1, offs, eadj, dinv, b2, h2a, N);

    bn_stats<<<256, 256, 0, stream>>>(h2a, bnsum, bnsq, N);
    bn_params<<<1, 256, 0, stream>>>(bnsum, bnsq, bng, bnb, bnscale, bnshift, N);
    bn_ln<<<(N + 3) / 4, 256, 0, stream>>>(h2a, bnscale, bnshift, lng, lnb, out, N);
}